// Round 1
// baseline (75224.164 us; speedup 1.0000x reference)
//
#include <hip/hip_runtime.h>
#include <math.h>

// Problem constants
#define BATCH   64
#define SEQLEN  128
#define EMBED   512
#define HID     1024
#define NSTEP   127          // seq-1 LSTM steps
#define OUT0    65           // first step index contributing to output
#define NOUT    62           // 127 - 65 outputs per batch

__device__ __forceinline__ float sigmoidf_(float x) { return 1.f / (1.f + expf(-x)); }

// One LSTM step, fused: gates GEMM + nonlinearities + c/h update + head partial.
// Grid: 256 blocks x 1024 threads. Block bid owns hidden units u = bid*4 .. bid*4+3.
// Thread t: b = t&63 (batch), q = t>>6: uu = q&3 (unit-in-block), ks = q>>2 (K-slice of 384).
// Each thread accumulates 4 gate partial dots (i,f,g,o for its unit) over its 384-wide K slice.
// xh = concat(x_t[b,0:512], h_t[b,0:1024]) staged in LDS in 8 tiles of 48 columns per slice.
__global__ __launch_bounds__(1024) void lstm_step(
    const int*   __restrict__ prob,
    const float* __restrict__ embed,
    const float* __restrict__ w_ih,
    const float* __restrict__ w_hh,
    const float* __restrict__ b_ih,
    const float* __restrict__ b_hh,
    const float* __restrict__ w_ans,
    const float* __restrict__ h_in,
    float*       __restrict__ h_out,
    float*       __restrict__ c_buf,
    float*       __restrict__ pout,
    int t)
{
    // 64 rows x (4*48 + 4 pad) = 64*196 words = 50176 B LDS.
    // Row stride 196: 196 % 32 == 4 -> lanes (=b) spread across banks for b128 reads.
    __shared__ float lds[64 * 196];

    const int tid = threadIdx.x;
    const int bid = blockIdx.x;
    const int b   = tid & 63;
    const int q   = tid >> 6;       // wave-uniform
    const int uu  = q & 3;
    const int ks  = q >> 2;         // 0..3
    const int u   = bid * 4 + uu;

    const float* wi0 = w_ih + (size_t)(0 * HID + u) * EMBED;
    const float* wi1 = w_ih + (size_t)(1 * HID + u) * EMBED;
    const float* wi2 = w_ih + (size_t)(2 * HID + u) * EMBED;
    const float* wi3 = w_ih + (size_t)(3 * HID + u) * EMBED;
    const float* wh0 = w_hh + (size_t)(0 * HID + u) * HID;
    const float* wh1 = w_hh + (size_t)(1 * HID + u) * HID;
    const float* wh2 = w_hh + (size_t)(2 * HID + u) * HID;
    const float* wh3 = w_hh + (size_t)(3 * HID + u) * HID;

    float a0 = 0.f, a1 = 0.f, a2 = 0.f, a3 = 0.f;

    for (int m = 0; m < 8; ++m) {
        // ---- stage xh tile: 64 rows x 192 words = 3072 float4 chunks, 3 per thread ----
        #pragma unroll
        for (int i2 = 0; i2 < 3; ++i2) {
            int id  = tid + (i2 << 10);      // 0..3071
            int row = id / 48;               // batch row
            int c4  = id - row * 48;         // float4 chunk in row
            int c   = c4 << 2;               // word col 0..188
            int kss = c / 48;                // K-slice group 0..3
            int kk  = c - kss * 48;
            int k   = kss * 384 + m * 48 + kk;  // global k in [0,1536)
            float4 v;
            if (k < EMBED) {
                int tok = prob[row * SEQLEN + t];
                v = *(const float4*)(embed + (size_t)tok * EMBED + k);
            } else {
                v = *(const float4*)(h_in + row * HID + (k - EMBED));
            }
            *(float4*)(&lds[row * 196 + c]) = v;
        }
        __syncthreads();

        // ---- compute: 12 float4 chunks of this thread's K slice ----
        const int kbase = ks * 384 + m * 48;
        #pragma unroll
        for (int c4 = 0; c4 < 12; ++c4) {
            int k = kbase + (c4 << 2);       // wave-uniform
            float4 xv = *(const float4*)(&lds[b * 196 + ks * 48 + (c4 << 2)]);
            float4 w0, w1, w2, w3;
            if (k < EMBED) {
                w0 = *(const float4*)(wi0 + k);
                w1 = *(const float4*)(wi1 + k);
                w2 = *(const float4*)(wi2 + k);
                w3 = *(const float4*)(wi3 + k);
            } else {
                int kh = k - EMBED;
                w0 = *(const float4*)(wh0 + kh);
                w1 = *(const float4*)(wh1 + kh);
                w2 = *(const float4*)(wh2 + kh);
                w3 = *(const float4*)(wh3 + kh);
            }
            a0 = fmaf(xv.x, w0.x, a0); a0 = fmaf(xv.y, w0.y, a0);
            a0 = fmaf(xv.z, w0.z, a0); a0 = fmaf(xv.w, w0.w, a0);
            a1 = fmaf(xv.x, w1.x, a1); a1 = fmaf(xv.y, w1.y, a1);
            a1 = fmaf(xv.z, w1.z, a1); a1 = fmaf(xv.w, w1.w, a1);
            a2 = fmaf(xv.x, w2.x, a2); a2 = fmaf(xv.y, w2.y, a2);
            a2 = fmaf(xv.z, w2.z, a2); a2 = fmaf(xv.w, w2.w, a2);
            a3 = fmaf(xv.x, w3.x, a3); a3 = fmaf(xv.y, w3.y, a3);
            a3 = fmaf(xv.z, w3.z, a3); a3 = fmaf(xv.w, w3.w, a3);
        }
        __syncthreads();
    }

    // ---- K-slice partials to LDS: part[g][ks][uu][b] ----
    lds[((0 * 4 + ks) * 4 + uu) * 64 + b] = a0;
    lds[((1 * 4 + ks) * 4 + uu) * 64 + b] = a1;
    lds[((2 * 4 + ks) * 4 + uu) * 64 + b] = a2;
    lds[((3 * 4 + ks) * 4 + uu) * 64 + b] = a3;
    __syncthreads();

    // ---- reduce + nonlinearity + state update (256 threads: 64 b x 4 units) ----
    if (tid < 256) {
        int bb  = tid & 63;
        int uu2 = tid >> 6;
        int u2  = bid * 4 + uu2;
        float s0 = 0.f, s1 = 0.f, s2 = 0.f, s3 = 0.f;
        #pragma unroll
        for (int k2 = 0; k2 < 4; ++k2) {
            s0 += lds[((0 * 4 + k2) * 4 + uu2) * 64 + bb];
            s1 += lds[((1 * 4 + k2) * 4 + uu2) * 64 + bb];
            s2 += lds[((2 * 4 + k2) * 4 + uu2) * 64 + bb];
            s3 += lds[((3 * 4 + k2) * 4 + uu2) * 64 + bb];
        }
        s0 += b_ih[0 * HID + u2] + b_hh[0 * HID + u2];
        s1 += b_ih[1 * HID + u2] + b_hh[1 * HID + u2];
        s2 += b_ih[2 * HID + u2] + b_hh[2 * HID + u2];
        s3 += b_ih[3 * HID + u2] + b_hh[3 * HID + u2];

        float ig = sigmoidf_(s0);
        float fg = sigmoidf_(s1);
        float gg = tanhf(s2);
        float og = sigmoidf_(s3);

        float co = c_buf[bb * HID + u2];
        float cn = fg * co + ig * gg;
        float hn = og * tanhf(cn);
        c_buf[bb * HID + u2] = cn;
        h_out[bb * HID + u2] = hn;

        // head partial: h * w_ans for this unit (store past partial region)
        lds[4096 + uu2 * 64 + bb] = hn * w_ans[u2];
    }
    __syncthreads();

    if (t >= OUT0 && tid < 64) {
        float s = lds[4096 + tid] + lds[4096 + 64 + tid] +
                  lds[4096 + 128 + tid] + lds[4096 + 192 + tid];
        // pout layout: [col][b][bid] for coalesced finalize reads
        pout[((size_t)((t - OUT0) * 64 + tid)) * 256 + bid] = s;
    }
}

// Reduce 256 block partials per (col, b), add bias, write out[b][col].
__global__ __launch_bounds__(64) void finalize_out(
    const float* __restrict__ pout,
    const float* __restrict__ b_ans,
    float*       __restrict__ out)
{
    int blk  = blockIdx.x;          // 0 .. NOUT*64-1
    int col  = blk >> 6;
    int bb   = blk & 63;
    int lane = threadIdx.x;
    const float* p = pout + (size_t)(col * 64 + bb) * 256;
    float s = p[lane] + p[lane + 64] + p[lane + 128] + p[lane + 192];
    #pragma unroll
    for (int off = 32; off > 0; off >>= 1) s += __shfl_down(s, off);
    if (lane == 0) out[bb * NOUT + col] = s + b_ans[0];
}

extern "C" void kernel_launch(void* const* d_in, const int* in_sizes, int n_in,
                              void* d_out, int out_size, void* d_ws, size_t ws_size,
                              hipStream_t stream)
{
    const int*   prob  = (const int*)  d_in[0];
    // d_in[1] = ans (unused by reference)
    const float* embed = (const float*)d_in[2];
    const float* w_ih  = (const float*)d_in[3];
    const float* w_hh  = (const float*)d_in[4];
    const float* b_ih  = (const float*)d_in[5];
    const float* b_hh  = (const float*)d_in[6];
    const float* w_ans = (const float*)d_in[7];
    const float* b_ans = (const float*)d_in[8];
    const float* h0    = (const float*)d_in[9];
    const float* c0    = (const float*)d_in[10];

    float* ws    = (float*)d_ws;
    float* hbuf0 = ws;                      // 64*1024
    float* hbuf1 = ws + 65536;              // 64*1024
    float* cbuf  = ws + 2 * 65536;          // 64*1024
    float* pout  = ws + 3 * 65536;          // 62*64*256 = 1,015,808 floats

    // init state from h0/c0 (ws is re-poisoned before every launch)
    hipMemcpyAsync(hbuf0, h0, (size_t)BATCH * HID * sizeof(float),
                   hipMemcpyDeviceToDevice, stream);
    hipMemcpyAsync(cbuf, c0, (size_t)BATCH * HID * sizeof(float),
                   hipMemcpyDeviceToDevice, stream);

    for (int t = 0; t < NSTEP; ++t) {
        float* hin  = (t & 1) ? hbuf1 : hbuf0;
        float* hout = (t & 1) ? hbuf0 : hbuf1;
        lstm_step<<<256, 1024, 0, stream>>>(prob, embed, w_ih, w_hh, b_ih, b_hh,
                                            w_ans, hin, hout, cbuf, pout, t);
    }
    finalize_out<<<NOUT * 64, 64, 0, stream>>>(pout, b_ans, (float*)d_out);
}

// Round 2
// 6990.101 us; speedup vs baseline: 10.7615x; 10.7615x over previous
//
#include <hip/hip_runtime.h>
#include <math.h>

#define BATCH   64
#define SEQLEN  128
#define EMBED   512
#define HID     1024
#define NSTEP   127
#define OUT0    65
#define NOUT    62
#define KTILE   128
#define NTILE   12
#define LSTR    68      // LDS row stride (words) for xh tile [k][b]

__device__ __forceinline__ float sigmoidf_(float x) { return 1.f / (1.f + expf(-x)); }

// Transpose h0/c0 (given [b][u]) into [u][b] working layout.
__global__ __launch_bounds__(256) void init_state(
    const float* __restrict__ h0, const float* __restrict__ c0,
    float* __restrict__ hT, float* __restrict__ cT)
{
    int id = blockIdx.x * 256 + threadIdx.x;   // 0..65535 = u*64+b
    int u = id >> 6, b = id & 63;
    hT[id] = h0[b * HID + u];
    cT[id] = c0[b * HID + u];
}

// Build xT[t][k][b] = embed[prob[b][t]][k] for t in 0..126 (one-time gather+transpose).
__global__ __launch_bounds__(256) void embed_transpose(
    const int* __restrict__ prob, const float* __restrict__ embed,
    float* __restrict__ xT)
{
    __shared__ float xe[64 * 132];
    int t = blockIdx.x;
    int tid = threadIdx.x;
    for (int kt = 0; kt < 4; ++kt) {
        #pragma unroll
        for (int i = 0; i < 8; ++i) {
            int id = tid + i * 256;          // 0..2047
            int b  = id >> 5;                // 0..63
            int k4 = id & 31;                // 0..31
            int tok = prob[b * SEQLEN + t];
            float4 v = *(const float4*)(embed + (size_t)tok * EMBED + kt * 128 + k4 * 4);
            *(float4*)(&xe[b * 132 + k4 * 4]) = v;
        }
        __syncthreads();
        #pragma unroll
        for (int i = 0; i < 8; ++i) {
            int id = tid + i * 256;
            int kl = id >> 4;                // 0..127
            int b4 = id & 15;
            float4 v;
            v.x = xe[(b4 * 4 + 0) * 132 + kl];
            v.y = xe[(b4 * 4 + 1) * 132 + kl];
            v.z = xe[(b4 * 4 + 2) * 132 + kl];
            v.w = xe[(b4 * 4 + 3) * 132 + kl];
            *(float4*)(&xT[((size_t)t * EMBED + kt * 128 + kl) * 64 + b4 * 4]) = v;
        }
        __syncthreads();
    }
}

// One LSTM step. 256 blocks x 256 threads. Block bid owns units bid*4..bid*4+3
// (16 gate-rows: 4 gates x 4 units) x all 64 batches.
// Thread (ks=tid>>6 wave = K-slice, lane: uu=lane&3 unit, bt=lane>>2 batch-quad):
// acc[gate][batch_sub] over K-slice of 384, tiled 128-K through LDS.
// Weights: global b128, each element read once per block (broadcast across 16 bt-lanes).
#define DO_GATE(J, W)                                                         \
    acc[J][0] = fmaf(W.x, xv0.x, acc[J][0]);                                  \
    acc[J][1] = fmaf(W.x, xv0.y, acc[J][1]);                                  \
    acc[J][2] = fmaf(W.x, xv0.z, acc[J][2]);                                  \
    acc[J][3] = fmaf(W.x, xv0.w, acc[J][3]);                                  \
    acc[J][0] = fmaf(W.y, xv1.x, acc[J][0]);                                  \
    acc[J][1] = fmaf(W.y, xv1.y, acc[J][1]);                                  \
    acc[J][2] = fmaf(W.y, xv1.z, acc[J][2]);                                  \
    acc[J][3] = fmaf(W.y, xv1.w, acc[J][3]);                                  \
    acc[J][0] = fmaf(W.z, xv2.x, acc[J][0]);                                  \
    acc[J][1] = fmaf(W.z, xv2.y, acc[J][1]);                                  \
    acc[J][2] = fmaf(W.z, xv2.z, acc[J][2]);                                  \
    acc[J][3] = fmaf(W.z, xv2.w, acc[J][3]);                                  \
    acc[J][0] = fmaf(W.w, xv3.x, acc[J][0]);                                  \
    acc[J][1] = fmaf(W.w, xv3.y, acc[J][1]);                                  \
    acc[J][2] = fmaf(W.w, xv3.z, acc[J][2]);                                  \
    acc[J][3] = fmaf(W.w, xv3.w, acc[J][3]);

__global__ __launch_bounds__(256) void lstm_step(
    const float* __restrict__ xT, const float* __restrict__ hT_in,
    float* __restrict__ hT_out, float* __restrict__ cT,
    const float* __restrict__ w_ih, const float* __restrict__ w_hh,
    const float* __restrict__ b_ih, const float* __restrict__ b_hh,
    const float* __restrict__ w_ans, float* __restrict__ pout, int t)
{
    __shared__ float lds[KTILE * LSTR];   // 8704 words; reused: [0,4096) reduce, [4096,4352) head
    const int tid  = threadIdx.x;
    const int bid  = blockIdx.x;
    const int ks   = tid >> 6;            // wave id = K-slice
    const int lane = tid & 63;
    const int uu   = lane & 3;
    const int bt   = lane >> 2;
    const int u    = bid * 4 + uu;

    const float* wi[4];
    const float* wh[4];
    #pragma unroll
    for (int j = 0; j < 4; ++j) {
        int rj = j * HID + u;
        wi[j] = w_ih + (size_t)rj * EMBED;
        wh[j] = w_hh + (size_t)rj * HID;
    }

    float acc[4][4];
    #pragma unroll
    for (int j = 0; j < 4; ++j)
        #pragma unroll
        for (int i = 0; i < 4; ++i) acc[j][i] = 0.f;

    const float* xt = xT + (size_t)t * EMBED * 64;

    for (int tile = 0; tile < NTILE; ++tile) {
        // stage xh tile [128 k][64 b] -> LDS, fully coalesced (sources are [.][b])
        const float* src = (tile < 4) ? (xt + tile * KTILE * 64)
                                      : (hT_in + (tile - 4) * KTILE * 64);
        #pragma unroll
        for (int i = 0; i < 8; ++i) {
            int id = tid + i * 256;
            int kl = id >> 4;
            int b4 = id & 15;
            float4 v = *(const float4*)(src + kl * 64 + b4 * 4);
            *(float4*)(&lds[kl * LSTR + b4 * 4]) = v;
        }
        __syncthreads();

        const int kw = tile * KTILE + ks * 32;   // this wave's global-k slice start
        #pragma unroll
        for (int kq = 0; kq < 8; ++kq) {
            int k = kw + kq * 4;
            float4 w0, w1, w2, w3;
            if (tile < 4) {
                w0 = *(const float4*)(wi[0] + k);
                w1 = *(const float4*)(wi[1] + k);
                w2 = *(const float4*)(wi[2] + k);
                w3 = *(const float4*)(wi[3] + k);
            } else {
                int kh = k - EMBED;
                w0 = *(const float4*)(wh[0] + kh);
                w1 = *(const float4*)(wh[1] + kh);
                w2 = *(const float4*)(wh[2] + kh);
                w3 = *(const float4*)(wh[3] + kh);
            }
            int klb = (ks * 32 + kq * 4) * LSTR + bt * 4;
            float4 xv0 = *(const float4*)(&lds[klb]);
            float4 xv1 = *(const float4*)(&lds[klb + LSTR]);
            float4 xv2 = *(const float4*)(&lds[klb + 2 * LSTR]);
            float4 xv3 = *(const float4*)(&lds[klb + 3 * LSTR]);
            DO_GATE(0, w0)
            DO_GATE(1, w1)
            DO_GATE(2, w2)
            DO_GATE(3, w3)
        }
        __syncthreads();
    }

    // K-slice partials -> LDS
    #pragma unroll
    for (int j = 0; j < 4; ++j)
        #pragma unroll
        for (int i = 0; i < 4; ++i)
            lds[((ks * 4 + uu) * 4 + j) * 64 + bt * 4 + i] = acc[j][i];
    __syncthreads();

    // reduce over 4 K-slices + nonlinearity + state update (all 256 threads: 4u x 64b)
    {
        int b   = tid & 63;
        int uu2 = tid >> 6;
        int u2  = bid * 4 + uu2;
        float s[4];
        #pragma unroll
        for (int j = 0; j < 4; ++j) {
            s[j] = lds[((0 * 4 + uu2) * 4 + j) * 64 + b]
                 + lds[((1 * 4 + uu2) * 4 + j) * 64 + b]
                 + lds[((2 * 4 + uu2) * 4 + j) * 64 + b]
                 + lds[((3 * 4 + uu2) * 4 + j) * 64 + b];
            int rj = j * HID + u2;
            s[j] += b_ih[rj] + b_hh[rj];
        }
        float ig = sigmoidf_(s[0]);
        float fg = sigmoidf_(s[1]);
        float gg = tanhf(s[2]);
        float og = sigmoidf_(s[3]);
        float cn = fg * cT[u2 * 64 + b] + ig * gg;
        float hn = og * tanhf(cn);
        cT[u2 * 64 + b]     = cn;   // block owns its units exclusively
        hT_out[u2 * 64 + b] = hn;
        lds[4096 + uu2 * 64 + b] = hn * w_ans[u2];   // head partial (disjoint LDS region)
    }
    __syncthreads();

    if (t >= OUT0 && tid < 64) {
        float sum = lds[4096 + tid] + lds[4096 + 64 + tid]
                  + lds[4096 + 128 + tid] + lds[4096 + 192 + tid];
        pout[((size_t)((t - OUT0) * 64 + tid)) * 256 + bid] = sum;
    }
}

// Reduce 256 block partials per (col, b), add bias, write out[b][col].
__global__ __launch_bounds__(64) void finalize_out(
    const float* __restrict__ pout,
    const float* __restrict__ b_ans,
    float*       __restrict__ out)
{
    int blk  = blockIdx.x;          // 0 .. NOUT*64-1
    int col  = blk >> 6;
    int bb   = blk & 63;
    int lane = threadIdx.x;
    const float* p = pout + (size_t)(col * 64 + bb) * 256;
    float s = p[lane] + p[lane + 64] + p[lane + 128] + p[lane + 192];
    #pragma unroll
    for (int off = 32; off > 0; off >>= 1) s += __shfl_down(s, off);
    if (lane == 0) out[bb * NOUT + col] = s + b_ans[0];
}

extern "C" void kernel_launch(void* const* d_in, const int* in_sizes, int n_in,
                              void* d_out, int out_size, void* d_ws, size_t ws_size,
                              hipStream_t stream)
{
    const int*   prob  = (const int*)  d_in[0];
    // d_in[1] = ans (unused)
    const float* embed = (const float*)d_in[2];
    const float* w_ih  = (const float*)d_in[3];
    const float* w_hh  = (const float*)d_in[4];
    const float* b_ih  = (const float*)d_in[5];
    const float* b_hh  = (const float*)d_in[6];
    const float* w_ans = (const float*)d_in[7];
    const float* b_ans = (const float*)d_in[8];
    const float* h0    = (const float*)d_in[9];
    const float* c0    = (const float*)d_in[10];

    float* ws   = (float*)d_ws;
    float* hT0  = ws;                    // 65536
    float* hT1  = ws + 65536;            // 65536
    float* cT   = ws + 131072;           // 65536
    float* pout = ws + 196608;           // 62*64*256 = 1,015,808
    float* xT   = ws + 1212416;          // 127*512*64 = 4,161,536  (total ~21.5 MB)

    init_state<<<256, 256, 0, stream>>>(h0, c0, hT0, cT);
    embed_transpose<<<NSTEP, 256, 0, stream>>>(prob, embed, xT);

    for (int t = 0; t < NSTEP; ++t) {
        float* hin  = (t & 1) ? hT1 : hT0;
        float* hout = (t & 1) ? hT0 : hT1;
        lstm_step<<<256, 256, 0, stream>>>(xT, hin, hout, cT, w_ih, w_hh,
                                           b_ih, b_hh, w_ans, pout, t);
    }
    finalize_out<<<NOUT * 64, 64, 0, stream>>>(pout, b_ans, (float*)d_out);
}

// Round 3
// 2756.335 us; speedup vs baseline: 27.2914x; 2.5360x over previous
//
#include <hip/hip_runtime.h>
#include <math.h>

#define BATCH   64
#define SEQLEN  128
#define EMBED   512
#define HID     1024
#define NSTEP   127
#define OUT0    65
#define NOUT    62
#define HEADOFF 4096     // LDS offset of head-partial region (floats)

__device__ __forceinline__ float sigmoidf_(float x) { return 1.f / (1.f + expf(-x)); }

// Transpose h0/c0 (given [b][u]) into [u][b] working layout.
__global__ __launch_bounds__(256) void init_state(
    const float* __restrict__ h0, const float* __restrict__ c0,
    float* __restrict__ hT, float* __restrict__ cT)
{
    int id = blockIdx.x * 256 + threadIdx.x;   // u*64+b
    int u = id >> 6, b = id & 63;
    hT[id] = h0[b * HID + u];
    cT[id] = c0[b * HID + u];
}

// Build xT[t][k][b] = embed[prob[b][t]][k] (one-time gather+transpose).
__global__ __launch_bounds__(256) void embed_transpose(
    const int* __restrict__ prob, const float* __restrict__ embed,
    float* __restrict__ xT)
{
    __shared__ float xe[64 * 132];
    int t = blockIdx.x;
    int tid = threadIdx.x;
    for (int kt = 0; kt < 4; ++kt) {
        #pragma unroll
        for (int i = 0; i < 8; ++i) {
            int id = tid + i * 256;
            int b  = id >> 5;
            int k4 = id & 31;
            int tok = prob[b * SEQLEN + t];
            float4 v = *(const float4*)(embed + (size_t)tok * EMBED + kt * 128 + k4 * 4);
            *(float4*)(&xe[b * 132 + k4 * 4]) = v;
        }
        __syncthreads();
        #pragma unroll
        for (int i = 0; i < 8; ++i) {
            int id = tid + i * 256;
            int kl = id >> 4;
            int b4 = id & 15;
            float4 v;
            v.x = xe[(b4 * 4 + 0) * 132 + kl];
            v.y = xe[(b4 * 4 + 1) * 132 + kl];
            v.z = xe[(b4 * 4 + 2) * 132 + kl];
            v.w = xe[(b4 * 4 + 3) * 132 + kl];
            *(float4*)(&xT[((size_t)t * EMBED + kt * 128 + kl) * 64 + b4 * 4]) = v;
        }
        __syncthreads();
    }
}

// One LSTM step. Grid 256 x 1024 threads (16 waves).
// Wave id ws (scalar): uu = ws&3 (unit-in-block), ksl = ws>>2 (K-slice 0..3).
// Lane = batch b. Weight addresses fully scalar -> s_load path (constant cache).
// xh[k][b] read as coalesced b32 from L2; no LDS staging, no loop barriers.
__global__ __launch_bounds__(1024, 4) void lstm_step(
    const float* __restrict__ xT, const float* __restrict__ hT_in,
    float* __restrict__ hT_out, float* __restrict__ cT,
    const float* __restrict__ w_ih, const float* __restrict__ w_hh,
    const float* __restrict__ b_ih, const float* __restrict__ b_hh,
    const float* __restrict__ w_ans, float* __restrict__ pout, int t)
{
    __shared__ float lds[HEADOFF + 256];   // 4096 reduce + 256 head = 17 KB
    const int tid = threadIdx.x;
    const int bid = blockIdx.x;
    const int b   = tid & 63;
    const int ws  = __builtin_amdgcn_readfirstlane(tid >> 6);  // scalar wave id
    const int uu  = ws & 3;
    const int ksl = ws >> 2;          // 0..3
    const int u   = bid * 4 + uu;     // scalar

    const float* wr_i[4];
    const float* wr_h[4];
    #pragma unroll
    for (int j = 0; j < 4; ++j) {
        wr_i[j] = w_ih + (size_t)(j * HID + u) * EMBED;
        wr_h[j] = w_hh + (size_t)(j * HID + u) * HID;
    }

    float acc[4];
    acc[0] = acc[1] = acc[2] = acc[3] = 0.f;

    // ---- x part: K-slice [ksl*128, ksl*128+128) of EMBED ----
    {
        const float* xt = xT + (size_t)t * EMBED * 64;
        const int k0 = ksl * 128;
        #pragma unroll 4
        for (int g = 0; g < 32; ++g) {
            const int k = k0 + g * 4;          // scalar
            float4 wv0 = *(const float4*)(wr_i[0] + k);
            float4 wv1 = *(const float4*)(wr_i[1] + k);
            float4 wv2 = *(const float4*)(wr_i[2] + k);
            float4 wv3 = *(const float4*)(wr_i[3] + k);
            float x0 = xt[(k + 0) * 64 + b];
            float x1 = xt[(k + 1) * 64 + b];
            float x2 = xt[(k + 2) * 64 + b];
            float x3 = xt[(k + 3) * 64 + b];
            acc[0] = fmaf(wv0.x, x0, acc[0]); acc[0] = fmaf(wv0.y, x1, acc[0]);
            acc[0] = fmaf(wv0.z, x2, acc[0]); acc[0] = fmaf(wv0.w, x3, acc[0]);
            acc[1] = fmaf(wv1.x, x0, acc[1]); acc[1] = fmaf(wv1.y, x1, acc[1]);
            acc[1] = fmaf(wv1.z, x2, acc[1]); acc[1] = fmaf(wv1.w, x3, acc[1]);
            acc[2] = fmaf(wv2.x, x0, acc[2]); acc[2] = fmaf(wv2.y, x1, acc[2]);
            acc[2] = fmaf(wv2.z, x2, acc[2]); acc[2] = fmaf(wv2.w, x3, acc[2]);
            acc[3] = fmaf(wv3.x, x0, acc[3]); acc[3] = fmaf(wv3.y, x1, acc[3]);
            acc[3] = fmaf(wv3.z, x2, acc[3]); acc[3] = fmaf(wv3.w, x3, acc[3]);
        }
    }
    // ---- h part: K-slice [ksl*256, ksl*256+256) of HID ----
    {
        const int k0 = ksl * 256;
        #pragma unroll 4
        for (int g = 0; g < 64; ++g) {
            const int k = k0 + g * 4;          // scalar
            float4 wv0 = *(const float4*)(wr_h[0] + k);
            float4 wv1 = *(const float4*)(wr_h[1] + k);
            float4 wv2 = *(const float4*)(wr_h[2] + k);
            float4 wv3 = *(const float4*)(wr_h[3] + k);
            float x0 = hT_in[(k + 0) * 64 + b];
            float x1 = hT_in[(k + 1) * 64 + b];
            float x2 = hT_in[(k + 2) * 64 + b];
            float x3 = hT_in[(k + 3) * 64 + b];
            acc[0] = fmaf(wv0.x, x0, acc[0]); acc[0] = fmaf(wv0.y, x1, acc[0]);
            acc[0] = fmaf(wv0.z, x2, acc[0]); acc[0] = fmaf(wv0.w, x3, acc[0]);
            acc[1] = fmaf(wv1.x, x0, acc[1]); acc[1] = fmaf(wv1.y, x1, acc[1]);
            acc[1] = fmaf(wv1.z, x2, acc[1]); acc[1] = fmaf(wv1.w, x3, acc[1]);
            acc[2] = fmaf(wv2.x, x0, acc[2]); acc[2] = fmaf(wv2.y, x1, acc[2]);
            acc[2] = fmaf(wv2.z, x2, acc[2]); acc[2] = fmaf(wv2.w, x3, acc[2]);
            acc[3] = fmaf(wv3.x, x0, acc[3]); acc[3] = fmaf(wv3.y, x1, acc[3]);
            acc[3] = fmaf(wv3.z, x2, acc[3]); acc[3] = fmaf(wv3.w, x3, acc[3]);
        }
    }

    // ---- partials to LDS: [ksl][uu][gate][b], lane-stride-1 (conflict-free) ----
    #pragma unroll
    for (int j = 0; j < 4; ++j)
        lds[((ksl * 4 + uu) * 4 + j) * 64 + b] = acc[j];
    __syncthreads();

    // ---- reduce 4 K-slices + nonlinearity + state update (tid<256: 4u x 64b) ----
    if (tid < 256) {
        int b2  = tid & 63;
        int uu2 = tid >> 6;
        int u2  = bid * 4 + uu2;
        float s[4];
        #pragma unroll
        for (int j = 0; j < 4; ++j) {
            s[j] = lds[((0 * 4 + uu2) * 4 + j) * 64 + b2]
                 + lds[((1 * 4 + uu2) * 4 + j) * 64 + b2]
                 + lds[((2 * 4 + uu2) * 4 + j) * 64 + b2]
                 + lds[((3 * 4 + uu2) * 4 + j) * 64 + b2];
            int rj = j * HID + u2;
            s[j] += b_ih[rj] + b_hh[rj];
        }
        float ig = sigmoidf_(s[0]);
        float fg = sigmoidf_(s[1]);
        float gg = tanhf(s[2]);
        float og = sigmoidf_(s[3]);
        float cn = fg * cT[u2 * 64 + b2] + ig * gg;
        float hn = og * tanhf(cn);
        cT[u2 * 64 + b2]     = cn;      // block owns its units exclusively
        hT_out[u2 * 64 + b2] = hn;
        lds[HEADOFF + uu2 * 64 + b2] = hn * w_ans[u2];
    }
    __syncthreads();

    if (t >= OUT0 && tid < 64) {
        float sum = lds[HEADOFF + tid]       + lds[HEADOFF + 64 + tid]
                  + lds[HEADOFF + 128 + tid] + lds[HEADOFF + 192 + tid];
        pout[((size_t)((t - OUT0) * 64 + tid)) * 256 + bid] = sum;
    }
}

// Reduce 256 block partials per (col, b), add bias, write out[b][col].
__global__ __launch_bounds__(64) void finalize_out(
    const float* __restrict__ pout,
    const float* __restrict__ b_ans,
    float*       __restrict__ out)
{
    int blk  = blockIdx.x;
    int col  = blk >> 6;
    int bb   = blk & 63;
    int lane = threadIdx.x;
    const float* p = pout + (size_t)(col * 64 + bb) * 256;
    float s = p[lane] + p[lane + 64] + p[lane + 128] + p[lane + 192];
    #pragma unroll
    for (int off = 32; off > 0; off >>= 1) s += __shfl_down(s, off);
    if (lane == 0) out[bb * NOUT + col] = s + b_ans[0];
}

extern "C" void kernel_launch(void* const* d_in, const int* in_sizes, int n_in,
                              void* d_out, int out_size, void* d_ws, size_t ws_size,
                              hipStream_t stream)
{
    const int*   prob  = (const int*)  d_in[0];
    const float* embed = (const float*)d_in[2];
    const float* w_ih  = (const float*)d_in[3];
    const float* w_hh  = (const float*)d_in[4];
    const float* b_ih  = (const float*)d_in[5];
    const float* b_hh  = (const float*)d_in[6];
    const float* w_ans = (const float*)d_in[7];
    const float* b_ans = (const float*)d_in[8];
    const float* h0    = (const float*)d_in[9];
    const float* c0    = (const float*)d_in[10];

    float* ws   = (float*)d_ws;
    float* hT0  = ws;                    // 65536
    float* hT1  = ws + 65536;            // 65536
    float* cT   = ws + 131072;           // 65536
    float* pout = ws + 196608;           // 62*64*256
    float* xT   = ws + 1212416;          // 127*512*64

    init_state<<<256, 256, 0, stream>>>(h0, c0, hT0, cT);
    embed_transpose<<<NSTEP, 256, 0, stream>>>(prob, embed, xT);

    for (int t = 0; t < NSTEP; ++t) {
        float* hin  = (t & 1) ? hT1 : hT0;
        float* hout = (t & 1) ? hT0 : hT1;
        lstm_step<<<256, 1024, 0, stream>>>(xT, hin, hout, cT, w_ih, w_hh,
                                            b_ih, b_hh, w_ans, pout, t);
    }
    finalize_out<<<NOUT * 64, 64, 0, stream>>>(pout, b_ans, (float*)d_out);
}